// Round 1
// baseline (12.393 us; speedup 1.0000x reference)
//
#include <hip/hip_runtime.h>
#include <math.h>

#define NCLASS 1000

__global__ __launch_bounds__(64) void focal_last_row_kernel(
    const float* __restrict__ outputs, long long row_off,
    const int* __restrict__ labels, int nlab,
    float* __restrict__ out)
{
    const float* row = outputs + row_off;
    const int lane = threadIdx.x;  // 0..63, one wave

    // Load 16 strided elements per lane (covers 0..1023 >= 1000)
    float v[16];
    float m = -INFINITY;
#pragma unroll
    for (int i = 0; i < 16; ++i) {
        int idx = lane + i * 64;
        v[i] = (idx < NCLASS) ? row[idx] : -INFINITY;
        m = fmaxf(m, v[i]);
    }

    // Wave-wide max reduce (64 lanes)
#pragma unroll
    for (int off = 1; off < 64; off <<= 1)
        m = fmaxf(m, __shfl_xor(m, off, 64));

    // Sum of exp(x - m); exp(-inf - m) = 0 handles the tail naturally
    float s = 0.0f;
#pragma unroll
    for (int i = 0; i < 16; ++i)
        s += expf(v[i] - m);

#pragma unroll
    for (int off = 1; off < 64; off <<= 1)
        s += __shfl_xor(s, off, 64);

    if (lane == 0) {
        const int c = labels[nlab - 1];
        const float xc = row[c];          // L1-hot re-read, fine
        const float logp = (xc - m) - logf(s);
        const float p = expf(logp);
        const float omp = 1.0f - p;
        float loss;
        if (c == 0) {
            loss = -0.1f * omp * omp * logp;
        } else if (c == 1) {
            loss = -0.9f * omp * omp * log1pf(-p);
        } else {
            loss = 0.0f;
        }
        out[0] = loss;
    }
}

extern "C" void kernel_launch(void* const* d_in, const int* in_sizes, int n_in,
                              void* d_out, int out_size, void* d_ws, size_t ws_size,
                              hipStream_t stream)
{
    const float* outputs = (const float*)d_in[0];
    const int*   labels  = (const int*)d_in[1];
    float*       out     = (float*)d_out;

    const long long total_out = (long long)in_sizes[0];   // 262144000, fits int32 but keep 64-bit
    const long long row_off   = total_out - NCLASS;       // start of last row
    const int       nlab      = in_sizes[1];

    focal_last_row_kernel<<<1, 64, 0, stream>>>(outputs, row_off, labels, nlab, out);
}